// Round 18
// baseline (548.204 us; speedup 1.0000x reference)
//
#include <hip/hip_runtime.h>
#include <hip/hip_bf16.h>

#define NN 100000
#define NE 3200000
#define D 64
#define BN_EPS 1e-5f

#define NP 512       // producer blocks
#define CHUNK 6250   // edges per producer (512*6250 = 3.2M exactly)
#define NB 391       // dst buckets of 256 nodes (391*256 = 100096 >= NN)
#define SPREAD 16    // stats contention spread

typedef float v2f __attribute__((ext_vector_type(2)));

#define FMA4(accr, xs, w4) \
  accr.x += (xs) * (w4).x; accr.y += (xs) * (w4).y; \
  accr.z += (xs) * (w4).z; accr.w += (xs) * (w4).w;

// ---- producer: bucket edges into private per-block regions.
//      rec = src | dstLocal<<17 | deg[src]<<25; 4-edge ILP batching. ----
__global__ __launch_bounds__(256) void bucket_kernel(const int* __restrict__ ei,
    const int* __restrict__ deg, int* __restrict__ rec, int* __restrict__ S) {
  __shared__ int cntL[392];
  __shared__ int curL[392];
  __shared__ int scanbuf[256];
  int t = threadIdx.x;
  int p = blockIdx.x;
  int e0 = p * CHUNK;
  cntL[t] = 0;
  if (t < 136) cntL[256 + t] = 0;
  __syncthreads();
  {
    int e = t;
    for (; e + 768 < CHUNK; e += 1024) {
      int d0 = ei[NE + e0 + e];
      int d1 = ei[NE + e0 + e + 256];
      int d2 = ei[NE + e0 + e + 512];
      int d3 = ei[NE + e0 + e + 768];
      atomicAdd(&cntL[(unsigned)d0 >> 8], 1);
      atomicAdd(&cntL[(unsigned)d1 >> 8], 1);
      atomicAdd(&cntL[(unsigned)d2 >> 8], 1);
      atomicAdd(&cntL[(unsigned)d3 >> 8], 1);
    }
    for (; e < CHUNK; e += 256) {
      int dd = ei[NE + e0 + e];
      atomicAdd(&cntL[(unsigned)dd >> 8], 1);
    }
  }
  __syncthreads();
  int a0 = 0, a1 = 0;
  if (t < 196) { a0 = cntL[2 * t]; a1 = cntL[2 * t + 1]; }
  int s = a0 + a1;
  scanbuf[t] = s;
  __syncthreads();
  for (int off = 1; off < 256; off <<= 1) {
    int x = (t >= off) ? scanbuf[t - off] : 0;
    __syncthreads();
    scanbuf[t] += x;
    __syncthreads();
  }
  int ex = scanbuf[t] - s;
  if (t < 196) {
    curL[2 * t]     = ex;
    curL[2 * t + 1] = ex + a0;
    S[p * 392 + 2 * t]     = e0 + ex;
    S[p * 392 + 2 * t + 1] = e0 + ex + a0;
  }
  __syncthreads();
  {
    int e = t;
    for (; e + 768 < CHUNK; e += 1024) {
      int s0 = ei[e0 + e],       d0 = ei[NE + e0 + e];
      int s1 = ei[e0 + e + 256], d1 = ei[NE + e0 + e + 256];
      int s2 = ei[e0 + e + 512], d2 = ei[NE + e0 + e + 512];
      int s3 = ei[e0 + e + 768], d3 = ei[NE + e0 + e + 768];
      int g0 = deg[s0], g1 = deg[s1], g2 = deg[s2], g3 = deg[s3];
      int p0 = atomicAdd(&curL[(unsigned)d0 >> 8], 1);
      int p1 = atomicAdd(&curL[(unsigned)d1 >> 8], 1);
      int p2 = atomicAdd(&curL[(unsigned)d2 >> 8], 1);
      int p3 = atomicAdd(&curL[(unsigned)d3 >> 8], 1);
      rec[e0 + p0] = s0 | ((d0 & 255) << 17) | (g0 << 25);
      rec[e0 + p1] = s1 | ((d1 & 255) << 17) | (g1 << 25);
      rec[e0 + p2] = s2 | ((d2 & 255) << 17) | (g2 << 25);
      rec[e0 + p3] = s3 | ((d3 & 255) << 17) | (g3 << 25);
    }
    for (; e < CHUNK; e += 256) {
      int ss = ei[e0 + e];
      int dd = ei[NE + e0 + e];
      int dg = deg[ss];
      int b = (unsigned)dd >> 8;
      int pos = atomicAdd(&curL[b], 1);
      rec[e0 + pos] = ss | ((dd & 255) << 17) | (dg << 25);
    }
  }
}

// ---- bucket totals ----
__global__ __launch_bounds__(256) void bucketsum_kernel(const int* __restrict__ S,
    int* __restrict__ bsum) {
  __shared__ int sh[256];
  int B = blockIdx.x;
  int t = threadIdx.x;
  int c = 0;
  for (int p = t; p < NP; p += 256)
    c += S[p * 392 + B + 1] - S[p * 392 + B];
  sh[t] = c;
  __syncthreads();
  for (int o = 128; o > 0; o >>= 1) {
    if (t < o) sh[t] += sh[t + o];
    __syncthreads();
  }
  if (t == 0) bsum[B] = sh[0];
}

// ---- exclusive scan of 391 bucket totals ----
__global__ __launch_bounds__(512) void scan2_kernel(int* __restrict__ bsum) {
  __shared__ int sh[512];
  int t = threadIdx.x;
  int v = (t < NB) ? bsum[t] : 0;
  sh[t] = v;
  __syncthreads();
  for (int o = 1; o < 512; o <<= 1) {
    int x = (t >= o) ? sh[t - o] : 0;
    __syncthreads();
    sh[t] += x;
    __syncthreads();
  }
  if (t < NB) bsum[t] = sh[t] - v;
}

// ---- sorter + neighbor-degree histogram (u16-packed, LDS 33 KB) ----
__global__ __launch_bounds__(512) void sort_kernel(const int* __restrict__ rec,
    const int* __restrict__ S, const int* __restrict__ bsum,
    int* __restrict__ csroff, int* __restrict__ csrsrc,
    unsigned* __restrict__ cnt8) {
  __shared__ int cntL[256];
  __shared__ int curL[256];
  __shared__ unsigned hist[256 * 33];
  int t = threadIdx.x;
  int B = blockIdx.x;
  if (t < 256) cntL[t] = 0;
  for (int k = t; k < 256 * 33; k += 512) hist[k] = 0;
  __syncthreads();
  int lane = t & 15;
  int g = t >> 4;
  for (int p = g; p < NP; p += 32) {
    int s0 = S[p * 392 + B], s1 = S[p * 392 + B + 1];
    for (int e = s0 + lane; e < s1; e += 16) {
      int r = rec[e];
      int dl = (r >> 17) & 255;
      int dg = (unsigned)r >> 25;
      atomicAdd(&cntL[dl], 1);
      atomicAdd(&hist[dl * 33 + (dg >> 1)], (dg & 1) ? 0x10000u : 1u);
    }
  }
  __syncthreads();
  int v = 0;
  if (t < 256) { v = cntL[t]; curL[t] = v; }
  __syncthreads();
  for (int o = 1; o < 256; o <<= 1) {
    int x = 0;
    if (t < 256 && t >= o) x = curL[t - o];
    __syncthreads();
    if (t < 256) curL[t] += x;
    __syncthreads();
  }
  int b0 = bsum[B];
  if (t < 256) {
    int excl = curL[t] - v;
    int node = B * 256 + t;
    if (node <= NN) csroff[node] = b0 + excl;
  }
  __syncthreads();
  if (t < 256) curL[t] = b0 + (curL[t] - v);
  if (t < 256) {
    int node = B * 256 + t;
    if (node < NN) {
      #pragma unroll
      for (int j = 0; j < 16; j++) {
        unsigned p0 = hist[t * 33 + 2 * j];
        unsigned p1 = hist[t * 33 + 2 * j + 1];
        unsigned p = (p0 & 255) | (((p0 >> 16) & 255) << 8)
                   | ((p1 & 255) << 16) | (((p1 >> 16) & 255) << 24);
        cnt8[(long)node * 16 + j] = p;
      }
    }
  }
  __syncthreads();
  for (int p = g; p < NP; p += 32) {
    int s0 = S[p * 392 + B], s1 = S[p * 392 + B + 1];
    for (int e = s0 + lane; e < s1; e += 16) {
      int r = rec[e];
      int pos = atomicAdd(&curL[(r >> 17) & 255], 1);
      csrsrc[pos] = r & 0x1FFFF;
    }
  }
}

// ---- fused layer (64 rows/block): inline fp8 aggregation (l>0) or
//      cnt8@embed (l==0), then z = (leaky(Xeff@W1+b1))@W2+b2 + stats ----
__global__ __launch_bounds__(256) void layer_kernel(
    const float* __restrict__ X,
    const int* __restrict__ off, const int* __restrict__ srcs,
    const unsigned* __restrict__ xh32,
    const unsigned* __restrict__ CNT8, const float* __restrict__ EMB,
    const int* __restrict__ deg, float* __restrict__ Z0,
    const float* __restrict__ epsv, int l,
    const float* __restrict__ W1, const float* __restrict__ b1,
    const float* __restrict__ W2, const float* __restrict__ b2,
    float* __restrict__ Z, float* __restrict__ spread)
{
  __shared__ float Ws[64][64];
  __shared__ float XsT[64][64];
  int t = threadIdx.x;
  int i0 = blockIdx.x * 64;
  float alpha = 1.0f + epsv[l];
  int c0 = (t & 15) * 4;
  int r0 = (t >> 4) * 4;
  int wr = t >> 4;
  int wc = (t & 15) * 4;
  int row = t & 63;
  int gi_row = i0 + row;
  int gis_row = (gi_row < NN) ? gi_row : NN - 1;
  int kb = (t >> 6) * 16;

  if (CNT8) {
    #pragma unroll
    for (int j = 0; j < 4; j++)
      *(float4*)&Ws[wr + 16 * j][wc] = *(const float4*)&EMB[(long)(wr + 16 * j) * D + wc];
    #pragma unroll
    for (int j = 0; j < 4; j++) {
      unsigned u = CNT8[(long)gis_row * 16 + (kb >> 2) + j];
      int k = kb + 4 * j;
      XsT[k + 0][row] = (float)(u & 255);
      XsT[k + 1][row] = (float)((u >> 8) & 255);
      XsT[k + 2][row] = (float)((u >> 16) & 255);
      XsT[k + 3][row] = (float)(u >> 24);
    }
    __syncthreads();
    float4 acc[4];
    #pragma unroll
    for (int r = 0; r < 4; r++) acc[r] = make_float4(0.f, 0.f, 0.f, 0.f);
    #pragma unroll 8
    for (int k = 0; k < 64; k++) {
      float4 w4 = *(const float4*)&Ws[k][c0];
      float4 x4 = *(const float4*)&XsT[k][r0];
      FMA4(acc[0], x4.x, w4); FMA4(acc[1], x4.y, w4);
      FMA4(acc[2], x4.z, w4); FMA4(acc[3], x4.w, w4);
    }
    __syncthreads();
    #pragma unroll
    for (int r = 0; r < 4; r++) {
      int gi = i0 + r0 + r;
      int gis = (gi < NN) ? gi : NN - 1;
      float4 xv = *(const float4*)&EMB[(long)deg[gis] * D + c0];
      if (gi < NN) *(float4*)&Z0[(long)gi * 256 + c0] = xv;
      XsT[c0 + 0][r0 + r] = alpha * xv.x + acc[r].x;
      XsT[c0 + 1][r0 + r] = alpha * xv.y + acc[r].y;
      XsT[c0 + 2][r0 + r] = alpha * xv.z + acc[r].z;
      XsT[c0 + 3][r0 + r] = alpha * xv.w + acc[r].w;
    }
    #pragma unroll
    for (int j = 0; j < 4; j++)
      *(float4*)&Ws[wr + 16 * j][wc] = *(const float4*)&W1[(long)(wr + 16 * j) * D + wc];
    __syncthreads();
  } else {
    #pragma unroll
    for (int j = 0; j < 4; j++)
      *(float4*)&Ws[wr + 16 * j][wc] = *(const float4*)&W1[(long)(wr + 16 * j) * D + wc];
    // inline aggregation: 16 groups x 16 lanes; group handles 4 rows.
    // Same per-node edge order + 4-edge unroll as old agg_kernel -> bitwise
    // identical sums. Lane holds dims 4*lane..4*lane+3 -> XsT[4*lane+j][r].
    {
      int lane = t & 15;
      int grp = t >> 4;        // 0..15
      #pragma unroll
      for (int rr = 0; rr < 4; rr++) {
        int r = grp * 4 + rr;
        int i = i0 + r;
        float s0 = 0.f, s1 = 0.f, s2 = 0.f, s3 = 0.f;
        if (i < NN) {
          int e0 = off[i], e1 = off[i + 1];
          int e = e0;
          for (; e + 4 <= e1; e += 4) {
            int j0 = srcs[e + 0], j1 = srcs[e + 1];
            int j2 = srcs[e + 2], j3 = srcs[e + 3];
            unsigned u0 = xh32[(long)j0 * 16 + lane];
            unsigned u1 = xh32[(long)j1 * 16 + lane];
            unsigned u2 = xh32[(long)j2 * 16 + lane];
            unsigned u3 = xh32[(long)j3 * 16 + lane];
            v2f l0 = __builtin_amdgcn_cvt_pk_f32_fp8((int)u0, false);
            v2f h0 = __builtin_amdgcn_cvt_pk_f32_fp8((int)u0, true);
            v2f l1 = __builtin_amdgcn_cvt_pk_f32_fp8((int)u1, false);
            v2f h1 = __builtin_amdgcn_cvt_pk_f32_fp8((int)u1, true);
            v2f l2 = __builtin_amdgcn_cvt_pk_f32_fp8((int)u2, false);
            v2f h2 = __builtin_amdgcn_cvt_pk_f32_fp8((int)u2, true);
            v2f l3 = __builtin_amdgcn_cvt_pk_f32_fp8((int)u3, false);
            v2f h3 = __builtin_amdgcn_cvt_pk_f32_fp8((int)u3, true);
            s0 += (l0.x + l1.x) + (l2.x + l3.x);
            s1 += (l0.y + l1.y) + (l2.y + l3.y);
            s2 += (h0.x + h1.x) + (h2.x + h3.x);
            s3 += (h0.y + h1.y) + (h2.y + h3.y);
          }
          for (; e < e1; e++) {
            unsigned u = xh32[(long)srcs[e] * 16 + lane];
            v2f lo = __builtin_amdgcn_cvt_pk_f32_fp8((int)u, false);
            v2f hi = __builtin_amdgcn_cvt_pk_f32_fp8((int)u, true);
            s0 += lo.x; s1 += lo.y; s2 += hi.x; s3 += hi.y;
          }
        }
        XsT[4 * lane + 0][r] = s0;
        XsT[4 * lane + 1][r] = s1;
        XsT[4 * lane + 2][r] = s2;
        XsT[4 * lane + 3][r] = s3;
      }
    }
    __syncthreads();
    // Xeff = alpha*x + agg (in-place RMW of XsT)
    #pragma unroll
    for (int j = 0; j < 4; j++) {
      int k = kb + 4 * j;
      float4 xv = *(const float4*)&X[(long)gis_row * 256 + k];
      XsT[k + 0][row] = alpha * xv.x + XsT[k + 0][row];
      XsT[k + 1][row] = alpha * xv.y + XsT[k + 1][row];
      XsT[k + 2][row] = alpha * xv.z + XsT[k + 2][row];
      XsT[k + 3][row] = alpha * xv.w + XsT[k + 3][row];
    }
    __syncthreads();
  }

  float4 h[4];
  {
    float4 b4 = *(const float4*)&b1[c0];
    #pragma unroll
    for (int r = 0; r < 4; r++) h[r] = b4;
  }
  #pragma unroll 8
  for (int k = 0; k < 64; k++) {
    float4 w4 = *(const float4*)&Ws[k][c0];
    float4 x4 = *(const float4*)&XsT[k][r0];
    FMA4(h[0], x4.x, w4); FMA4(h[1], x4.y, w4);
    FMA4(h[2], x4.z, w4); FMA4(h[3], x4.w, w4);
  }
  #pragma unroll
  for (int r = 0; r < 4; r++) {
    h[r].x = (h[r].x >= 0.0f) ? h[r].x : 0.01f * h[r].x;
    h[r].y = (h[r].y >= 0.0f) ? h[r].y : 0.01f * h[r].y;
    h[r].z = (h[r].z >= 0.0f) ? h[r].z : 0.01f * h[r].z;
    h[r].w = (h[r].w >= 0.0f) ? h[r].w : 0.01f * h[r].w;
  }
  __syncthreads();
  #pragma unroll
  for (int r = 0; r < 4; r++) {
    XsT[c0 + 0][r0 + r] = h[r].x;
    XsT[c0 + 1][r0 + r] = h[r].y;
    XsT[c0 + 2][r0 + r] = h[r].z;
    XsT[c0 + 3][r0 + r] = h[r].w;
  }
  #pragma unroll
  for (int j = 0; j < 4; j++)
    *(float4*)&Ws[wr + 16 * j][wc] = *(const float4*)&W2[(long)(wr + 16 * j) * D + wc];
  __syncthreads();

  float4 z[4];
  {
    float4 b4 = *(const float4*)&b2[c0];
    #pragma unroll
    for (int r = 0; r < 4; r++) z[r] = b4;
  }
  #pragma unroll 8
  for (int k = 0; k < 64; k++) {
    float4 w4 = *(const float4*)&Ws[k][c0];
    float4 x4 = *(const float4*)&XsT[k][r0];
    FMA4(z[0], x4.x, w4); FMA4(z[1], x4.y, w4);
    FMA4(z[2], x4.z, w4); FMA4(z[3], x4.w, w4);
  }
  #pragma unroll
  for (int r = 0; r < 4; r++) {
    int gi = i0 + r0 + r;
    if (gi < NN) *(float4*)&Z[(long)gi * 256 + c0] = z[r];
  }

  float s[4] = {0, 0, 0, 0}, sq[4] = {0, 0, 0, 0};
  #pragma unroll
  for (int r = 0; r < 4; r++) {
    if (i0 + r0 + r < NN) {
      s[0] += z[r].x; sq[0] += z[r].x * z[r].x;
      s[1] += z[r].y; sq[1] += z[r].y * z[r].y;
      s[2] += z[r].z; sq[2] += z[r].z * z[r].z;
      s[3] += z[r].w; sq[3] += z[r].w * z[r].w;
    }
  }
  __syncthreads();
  float* red = &XsT[0][0];
  int grp = t >> 4;
  #pragma unroll
  for (int j = 0; j < 4; j++) {
    red[grp * 64 + c0 + j] = s[j];
    red[1024 + grp * 64 + c0 + j] = sq[j];
  }
  __syncthreads();
  if (t < 64) {
    float a = 0.0f, b = 0.0f;
    #pragma unroll
    for (int g = 0; g < 16; g++) {
      a += red[g * 64 + t];
      b += red[1024 + g * 64 + t];
    }
    int slot = blockIdx.x & (SPREAD - 1);
    atomicAdd(&spread[slot * 128 + t], a);
    atomicAdd(&spread[slot * 128 + 64 + t], b);
  }
}

// ---- fc1 (64 rows/block): K=256 gemm + BN partial stats ----
__global__ __launch_bounds__(256) void fc1_kernel(
    const float* __restrict__ X,
    const float* __restrict__ W, const float* __restrict__ bias,
    float* __restrict__ Y, float* __restrict__ spread)
{
  __shared__ float Ws[64][64];
  __shared__ float XsT[64][64];
  int t = threadIdx.x;
  int i0 = blockIdx.x * 64;
  int c0 = (t & 15) * 4;
  int r0 = (t >> 4) * 4;
  int wr = t >> 4;
  int wc = (t & 15) * 4;

  float4 acc[4];
  {
    float4 b4 = *(const float4*)&bias[c0];
    #pragma unroll
    for (int r = 0; r < 4; r++) acc[r] = b4;
  }
  for (int kc = 0; kc < 256; kc += 64) {
    __syncthreads();
    #pragma unroll
    for (int j = 0; j < 4; j++)
      *(float4*)&Ws[wr + 16 * j][wc] = *(const float4*)&W[(long)(kc + wr + 16 * j) * D + wc];
    {
      int row = t & 63;
      int gi = i0 + row;
      int gis = (gi < NN) ? gi : NN - 1;
      int kb = (t >> 6) * 16;
      #pragma unroll
      for (int j = 0; j < 4; j++) {
        int k = kb + 4 * j;
        float4 xv = *(const float4*)&X[(long)gis * 256 + kc + k];
        XsT[k + 0][row] = xv.x;
        XsT[k + 1][row] = xv.y;
        XsT[k + 2][row] = xv.z;
        XsT[k + 3][row] = xv.w;
      }
    }
    __syncthreads();
    #pragma unroll 8
    for (int k = 0; k < 64; k++) {
      float4 w4 = *(const float4*)&Ws[k][c0];
      float4 x4 = *(const float4*)&XsT[k][r0];
      FMA4(acc[0], x4.x, w4); FMA4(acc[1], x4.y, w4);
      FMA4(acc[2], x4.z, w4); FMA4(acc[3], x4.w, w4);
    }
  }
  #pragma unroll
  for (int r = 0; r < 4; r++) {
    int gi = i0 + r0 + r;
    if (gi < NN) *(float4*)&Y[(long)gi * D + c0] = acc[r];
  }
  float s[4] = {0, 0, 0, 0}, sq[4] = {0, 0, 0, 0};
  #pragma unroll
  for (int r = 0; r < 4; r++) {
    if (i0 + r0 + r < NN) {
      s[0] += acc[r].x; sq[0] += acc[r].x * acc[r].x;
      s[1] += acc[r].y; sq[1] += acc[r].y * acc[r].y;
      s[2] += acc[r].z; sq[2] += acc[r].z * acc[r].z;
      s[3] += acc[r].w; sq[3] += acc[r].w * acc[r].w;
    }
  }
  __syncthreads();
  float* red = &XsT[0][0];
  int grp = t >> 4;
  #pragma unroll
  for (int j = 0; j < 4; j++) {
    red[grp * 64 + c0 + j] = s[j];
    red[1024 + grp * 64 + c0 + j] = sq[j];
  }
  __syncthreads();
  if (t < 64) {
    float a = 0.0f, b = 0.0f;
    #pragma unroll
    for (int g = 0; g < 16; g++) {
      a += red[g * 64 + t];
      b += red[1024 + g * 64 + t];
    }
    int slot = blockIdx.x & (SPREAD - 1);
    atomicAdd(&spread[slot * 128 + t], a);
    atomicAdd(&spread[slot * 128 + 64 + t], b);
  }
}

// ---- BN apply + leaky (zcat in place) + fp8 [N][64] mirror; reduces
//      SPREAD slots per block (same g-order -> bitwise identical stats) ----
__global__ __launch_bounds__(256) void bn_apply_kernel(float* __restrict__ Zs,
    const float* __restrict__ spread,
    const float* __restrict__ g, const float* __restrict__ b,
    unsigned short* __restrict__ Outh) {
  __shared__ float st[128];
  int t = threadIdx.x;
  if (t < 128) {
    float a = 0.0f;
    #pragma unroll
    for (int gg = 0; gg < SPREAD; gg++) a += spread[gg * 128 + t];
    st[t] = a;
  }
  __syncthreads();
  int idx = blockIdx.x * 256 + t;   // over NN*32 pairs
  int i = idx >> 5, dp = (idx & 31) * 2;
  if (i >= NN) return;
  float invn = 1.0f / (float)NN;
  float v0, v1;
  {
    float mu = st[dp] * invn;
    float var = fmaxf(st[64 + dp] * invn - mu * mu, 0.0f);
    float sc = g[dp] * rsqrtf(var + BN_EPS);
    v0 = sc * (Zs[(long)i * 256 + dp] - mu) + b[dp];
    v0 = (v0 >= 0.0f) ? v0 : 0.01f * v0;
  }
  {
    float mu = st[dp + 1] * invn;
    float var = fmaxf(st[64 + dp + 1] * invn - mu * mu, 0.0f);
    float sc = g[dp + 1] * rsqrtf(var + BN_EPS);
    v1 = sc * (Zs[(long)i * 256 + dp + 1] - mu) + b[dp + 1];
    v1 = (v1 >= 0.0f) ? v1 : 0.01f * v1;
  }
  Zs[(long)i * 256 + dp]     = v0;
  Zs[(long)i * 256 + dp + 1] = v1;
  if (Outh) {
    int packed = __builtin_amdgcn_cvt_pk_fp8_f32(v0, v1, 0, false);
    Outh[(long)i * 32 + (dp >> 1)] = (unsigned short)packed;
  }
}

// ---- fused fc BN-apply + fc2 dot + sigmoid (reduces SPREAD per block) ----
__global__ __launch_bounds__(256) void fc2bn_kernel(const float* __restrict__ H,
    const float* __restrict__ spread,
    const float* __restrict__ g, const float* __restrict__ b,
    const float* __restrict__ W2, const float* __restrict__ b2,
    float* __restrict__ out) {
  __shared__ float st[128];
  int tid = threadIdx.x;
  if (tid < 128) {
    float a = 0.0f;
    #pragma unroll
    for (int gg = 0; gg < SPREAD; gg++) a += spread[gg * 128 + tid];
    st[tid] = a;
  }
  __syncthreads();
  int k = tid & 63, q = tid >> 6;
  int i = blockIdx.x * 4 + q;
  float invn = 1.0f / (float)NN;
  float mu = st[k] * invn;
  float var = fmaxf(st[64 + k] * invn - mu * mu, 0.0f);
  float sc = g[k] * rsqrtf(var + BN_EPS);
  float v = 0.0f;
  if (i < NN) {
    float hv = sc * (H[(long)i * D + k] - mu) + b[k];
    hv = (hv >= 0.0f) ? hv : 0.01f * hv;
    v = hv * W2[k];
  }
  #pragma unroll
  for (int off = 32; off > 0; off >>= 1)
    v += __shfl_down(v, off);
  if (k == 0 && i < NN) {
    float x = v + b2[0];
    out[i] = 1.0f / (1.0f + __expf(-x));
  }
}

extern "C" void kernel_launch(void* const* d_in, const int* in_sizes, int n_in,
                              void* d_out, int out_size, void* d_ws, size_t ws_size,
                              hipStream_t stream) {
  const int*   node_deg   = (const int*)d_in[0];
  const int*   edge_index = (const int*)d_in[1];
  const float* embedw     = (const float*)d_in[2];
  const float* eps        = (const float*)d_in[3];
  const float* W1         = (const float*)d_in[4];
  const float* b1         = (const float*)d_in[5];
  const float* W2         = (const float*)d_in[6];
  const float* b2         = (const float*)d_in[7];
  const float* bn_g       = (const float*)d_in[8];
  const float* bn_b       = (const float*)d_in[9];
  const float* fc_W1      = (const float*)d_in[10];
  const float* fc_b1      = (const float*)d_in[11];
  const float* fc_bn_g    = (const float*)d_in[12];
  const float* fc_bn_b    = (const float*)d_in[13];
  const float* fc_W2      = (const float*)d_in[14];
  const float* fc_b2      = (const float*)d_in[15];

  float* zcat   = (float*)d_ws;                 // [N,256]
  float* agg    = zcat + (long)NN * 256;        // [N,64] (fc1 pre-BN output)
  float* statsS = agg + (long)NN * D;           // 4 * SPREAD*128
  float* statsF = statsS + 4 * SPREAD * 128;    // layout keep
  int*   csroff = (int*)(statsF + 512);         // [NN+1]
  int*   bsum   = csroff + NN + 1;              // [512]
  int*   csrsrc = bsum + 512;                   // [NE]
  int*   rec    = csrsrc + NE;                  // [NE]
  int*   S      = rec + NE;                     // [NP*392]
  unsigned* cnt8 = (unsigned*)(S + NP * 392);   // [N,16] u32
  unsigned short* xh = (unsigned short*)rec;    // fp8 mirror [N][64] overlays rec

  const int rowBlocks   = NN / 4;                 // 25000
  const int layerBlocks = (NN + 63) / 64;         // 1563
  const int bnBlocks    = (NN * 32 + 255) / 256;  // 12500

  bucket_kernel<<<NP, 256, 0, stream>>>(edge_index, node_deg, rec, S);
  bucketsum_kernel<<<NB, 256, 0, stream>>>(S, bsum);
  scan2_kernel<<<1, 512, 0, stream>>>(bsum);
  sort_kernel<<<NB, 512, 0, stream>>>(rec, S, bsum, csroff, csrsrc, cnt8);

  hipMemsetAsync(statsS, 0, (size_t)(4 * SPREAD * 128) * sizeof(float), stream);

  for (int l = 0; l < 3; ++l) {
    layer_kernel<<<layerBlocks, 256, 0, stream>>>(zcat + l * D,
        csroff, csrsrc, (const unsigned*)xh,
        (l == 0) ? cnt8 : nullptr, embedw, node_deg, zcat,
        eps, l,
        W1 + (long)l * D * D, b1 + (long)l * D,
        W2 + (long)l * D * D, b2 + (long)l * D,
        zcat + (l + 1) * D, statsS + (long)l * SPREAD * 128);
    bn_apply_kernel<<<bnBlocks, 256, 0, stream>>>(zcat + (l + 1) * D,
        statsS + (long)l * SPREAD * 128,
        bn_g + (long)l * D, bn_b + (long)l * D,
        (l < 2) ? xh : nullptr);
  }

  fc1_kernel<<<layerBlocks, 256, 0, stream>>>(zcat, fc_W1, fc_b1, agg,
      statsS + 3L * SPREAD * 128);
  fc2bn_kernel<<<rowBlocks, 256, 0, stream>>>(agg, statsS + 3L * SPREAD * 128,
      fc_bn_g, fc_bn_b, fc_W2, fc_b2, (float*)d_out);
}

// Round 19
// 509.562 us; speedup vs baseline: 1.0758x; 1.0758x over previous
//
#include <hip/hip_runtime.h>
#include <hip/hip_bf16.h>

#define NN 100000
#define NE 3200000
#define D 64
#define BN_EPS 1e-5f

#define NP 512       // producer blocks
#define CHUNK 6250   // edges per producer (512*6250 = 3.2M exactly)
#define NB 391       // dst buckets of 256 nodes (391*256 = 100096 >= NN)
#define SPREAD 16    // stats contention spread

typedef float v2f __attribute__((ext_vector_type(2)));

#define FMA4(accr, xs, w4) \
  accr.x += (xs) * (w4).x; accr.y += (xs) * (w4).y; \
  accr.z += (xs) * (w4).z; accr.w += (xs) * (w4).w;

// ---- producer: bucket edges into private per-block regions.
//      rec = src | dstLocal<<17 | deg[src]<<25; 4-edge ILP batching. ----
__global__ __launch_bounds__(256) void bucket_kernel(const int* __restrict__ ei,
    const int* __restrict__ deg, int* __restrict__ rec, int* __restrict__ S) {
  __shared__ int cntL[392];
  __shared__ int curL[392];
  __shared__ int scanbuf[256];
  int t = threadIdx.x;
  int p = blockIdx.x;
  int e0 = p * CHUNK;
  cntL[t] = 0;
  if (t < 136) cntL[256 + t] = 0;
  __syncthreads();
  {
    int e = t;
    for (; e + 768 < CHUNK; e += 1024) {
      int d0 = ei[NE + e0 + e];
      int d1 = ei[NE + e0 + e + 256];
      int d2 = ei[NE + e0 + e + 512];
      int d3 = ei[NE + e0 + e + 768];
      atomicAdd(&cntL[(unsigned)d0 >> 8], 1);
      atomicAdd(&cntL[(unsigned)d1 >> 8], 1);
      atomicAdd(&cntL[(unsigned)d2 >> 8], 1);
      atomicAdd(&cntL[(unsigned)d3 >> 8], 1);
    }
    for (; e < CHUNK; e += 256) {
      int dd = ei[NE + e0 + e];
      atomicAdd(&cntL[(unsigned)dd >> 8], 1);
    }
  }
  __syncthreads();
  int a0 = 0, a1 = 0;
  if (t < 196) { a0 = cntL[2 * t]; a1 = cntL[2 * t + 1]; }
  int s = a0 + a1;
  scanbuf[t] = s;
  __syncthreads();
  for (int off = 1; off < 256; off <<= 1) {
    int x = (t >= off) ? scanbuf[t - off] : 0;
    __syncthreads();
    scanbuf[t] += x;
    __syncthreads();
  }
  int ex = scanbuf[t] - s;
  if (t < 196) {
    curL[2 * t]     = ex;
    curL[2 * t + 1] = ex + a0;
    S[p * 392 + 2 * t]     = e0 + ex;
    S[p * 392 + 2 * t + 1] = e0 + ex + a0;
  }
  __syncthreads();
  {
    int e = t;
    for (; e + 768 < CHUNK; e += 1024) {
      int s0 = ei[e0 + e],       d0 = ei[NE + e0 + e];
      int s1 = ei[e0 + e + 256], d1 = ei[NE + e0 + e + 256];
      int s2 = ei[e0 + e + 512], d2 = ei[NE + e0 + e + 512];
      int s3 = ei[e0 + e + 768], d3 = ei[NE + e0 + e + 768];
      int g0 = deg[s0], g1 = deg[s1], g2 = deg[s2], g3 = deg[s3];
      int p0 = atomicAdd(&curL[(unsigned)d0 >> 8], 1);
      int p1 = atomicAdd(&curL[(unsigned)d1 >> 8], 1);
      int p2 = atomicAdd(&curL[(unsigned)d2 >> 8], 1);
      int p3 = atomicAdd(&curL[(unsigned)d3 >> 8], 1);
      rec[e0 + p0] = s0 | ((d0 & 255) << 17) | (g0 << 25);
      rec[e0 + p1] = s1 | ((d1 & 255) << 17) | (g1 << 25);
      rec[e0 + p2] = s2 | ((d2 & 255) << 17) | (g2 << 25);
      rec[e0 + p3] = s3 | ((d3 & 255) << 17) | (g3 << 25);
    }
    for (; e < CHUNK; e += 256) {
      int ss = ei[e0 + e];
      int dd = ei[NE + e0 + e];
      int dg = deg[ss];
      int b = (unsigned)dd >> 8;
      int pos = atomicAdd(&curL[b], 1);
      rec[e0 + pos] = ss | ((dd & 255) << 17) | (dg << 25);
    }
  }
}

// ---- bucket totals ----
__global__ __launch_bounds__(256) void bucketsum_kernel(const int* __restrict__ S,
    int* __restrict__ bsum) {
  __shared__ int sh[256];
  int B = blockIdx.x;
  int t = threadIdx.x;
  int c = 0;
  for (int p = t; p < NP; p += 256)
    c += S[p * 392 + B + 1] - S[p * 392 + B];
  sh[t] = c;
  __syncthreads();
  for (int o = 128; o > 0; o >>= 1) {
    if (t < o) sh[t] += sh[t + o];
    __syncthreads();
  }
  if (t == 0) bsum[B] = sh[0];
}

// ---- exclusive scan of 391 bucket totals ----
__global__ __launch_bounds__(512) void scan2_kernel(int* __restrict__ bsum) {
  __shared__ int sh[512];
  int t = threadIdx.x;
  int v = (t < NB) ? bsum[t] : 0;
  sh[t] = v;
  __syncthreads();
  for (int o = 1; o < 512; o <<= 1) {
    int x = (t >= o) ? sh[t - o] : 0;
    __syncthreads();
    sh[t] += x;
    __syncthreads();
  }
  if (t < NB) bsum[t] = sh[t] - v;
}

// ---- sorter + neighbor-degree histogram (u16-packed, LDS 33 KB) ----
__global__ __launch_bounds__(512) void sort_kernel(const int* __restrict__ rec,
    const int* __restrict__ S, const int* __restrict__ bsum,
    int* __restrict__ csroff, int* __restrict__ csrsrc,
    unsigned* __restrict__ cnt8) {
  __shared__ int cntL[256];
  __shared__ int curL[256];
  __shared__ unsigned hist[256 * 33];
  int t = threadIdx.x;
  int B = blockIdx.x;
  if (t < 256) cntL[t] = 0;
  for (int k = t; k < 256 * 33; k += 512) hist[k] = 0;
  __syncthreads();
  int lane = t & 15;
  int g = t >> 4;
  for (int p = g; p < NP; p += 32) {
    int s0 = S[p * 392 + B], s1 = S[p * 392 + B + 1];
    for (int e = s0 + lane; e < s1; e += 16) {
      int r = rec[e];
      int dl = (r >> 17) & 255;
      int dg = (unsigned)r >> 25;
      atomicAdd(&cntL[dl], 1);
      atomicAdd(&hist[dl * 33 + (dg >> 1)], (dg & 1) ? 0x10000u : 1u);
    }
  }
  __syncthreads();
  int v = 0;
  if (t < 256) { v = cntL[t]; curL[t] = v; }
  __syncthreads();
  for (int o = 1; o < 256; o <<= 1) {
    int x = 0;
    if (t < 256 && t >= o) x = curL[t - o];
    __syncthreads();
    if (t < 256) curL[t] += x;
    __syncthreads();
  }
  int b0 = bsum[B];
  if (t < 256) {
    int excl = curL[t] - v;
    int node = B * 256 + t;
    if (node <= NN) csroff[node] = b0 + excl;
  }
  __syncthreads();
  if (t < 256) curL[t] = b0 + (curL[t] - v);
  if (t < 256) {
    int node = B * 256 + t;
    if (node < NN) {
      #pragma unroll
      for (int j = 0; j < 16; j++) {
        unsigned p0 = hist[t * 33 + 2 * j];
        unsigned p1 = hist[t * 33 + 2 * j + 1];
        unsigned p = (p0 & 255) | (((p0 >> 16) & 255) << 8)
                   | ((p1 & 255) << 16) | (((p1 >> 16) & 255) << 24);
        cnt8[(long)node * 16 + j] = p;
      }
    }
  }
  __syncthreads();
  for (int p = g; p < NP; p += 32) {
    int s0 = S[p * 392 + B], s1 = S[p * 392 + B + 1];
    for (int e = s0 + lane; e < s1; e += 16) {
      int r = rec[e];
      int pos = atomicAdd(&curL[(r >> 17) & 255], 1);
      csrsrc[pos] = r & 0x1FFFF;
    }
  }
}

// ---- aggregation (layers 1,2): fp8 e4m3 [N][64], one line touch/edge.
//      8 loads in flight; FP adds in the ORIGINAL 4-batch order
//      (bitwise identical to the 4-deep version). ----
__global__ __launch_bounds__(256) void agg_kernel(const int* __restrict__ off,
    const int* __restrict__ srcs, const unsigned* __restrict__ xh32,
    float* __restrict__ agg) {
  int t = threadIdx.x;
  int lane = t & 15;
  int g = t >> 4;
  int i = blockIdx.x * 16 + g;
  int e0 = off[i], e1 = off[i + 1];
  float s0 = 0.f, s1 = 0.f, s2 = 0.f, s3 = 0.f;
  int e = e0;
  for (; e + 8 <= e1; e += 8) {
    int j0 = srcs[e + 0], j1 = srcs[e + 1], j2 = srcs[e + 2], j3 = srcs[e + 3];
    int j4 = srcs[e + 4], j5 = srcs[e + 5], j6 = srcs[e + 6], j7 = srcs[e + 7];
    unsigned u0 = xh32[(long)j0 * 16 + lane];
    unsigned u1 = xh32[(long)j1 * 16 + lane];
    unsigned u2 = xh32[(long)j2 * 16 + lane];
    unsigned u3 = xh32[(long)j3 * 16 + lane];
    unsigned u4 = xh32[(long)j4 * 16 + lane];
    unsigned u5 = xh32[(long)j5 * 16 + lane];
    unsigned u6 = xh32[(long)j6 * 16 + lane];
    unsigned u7 = xh32[(long)j7 * 16 + lane];
    // batch A (same add order as original first 4-batch)
    {
      v2f l0 = __builtin_amdgcn_cvt_pk_f32_fp8((int)u0, false);
      v2f h0 = __builtin_amdgcn_cvt_pk_f32_fp8((int)u0, true);
      v2f l1 = __builtin_amdgcn_cvt_pk_f32_fp8((int)u1, false);
      v2f h1 = __builtin_amdgcn_cvt_pk_f32_fp8((int)u1, true);
      v2f l2 = __builtin_amdgcn_cvt_pk_f32_fp8((int)u2, false);
      v2f h2 = __builtin_amdgcn_cvt_pk_f32_fp8((int)u2, true);
      v2f l3 = __builtin_amdgcn_cvt_pk_f32_fp8((int)u3, false);
      v2f h3 = __builtin_amdgcn_cvt_pk_f32_fp8((int)u3, true);
      s0 += (l0.x + l1.x) + (l2.x + l3.x);
      s1 += (l0.y + l1.y) + (l2.y + l3.y);
      s2 += (h0.x + h1.x) + (h2.x + h3.x);
      s3 += (h0.y + h1.y) + (h2.y + h3.y);
    }
    // batch B (same add order as original second 4-batch)
    {
      v2f l0 = __builtin_amdgcn_cvt_pk_f32_fp8((int)u4, false);
      v2f h0 = __builtin_amdgcn_cvt_pk_f32_fp8((int)u4, true);
      v2f l1 = __builtin_amdgcn_cvt_pk_f32_fp8((int)u5, false);
      v2f h1 = __builtin_amdgcn_cvt_pk_f32_fp8((int)u5, true);
      v2f l2 = __builtin_amdgcn_cvt_pk_f32_fp8((int)u6, false);
      v2f h2 = __builtin_amdgcn_cvt_pk_f32_fp8((int)u6, true);
      v2f l3 = __builtin_amdgcn_cvt_pk_f32_fp8((int)u7, false);
      v2f h3 = __builtin_amdgcn_cvt_pk_f32_fp8((int)u7, true);
      s0 += (l0.x + l1.x) + (l2.x + l3.x);
      s1 += (l0.y + l1.y) + (l2.y + l3.y);
      s2 += (h0.x + h1.x) + (h2.x + h3.x);
      s3 += (h0.y + h1.y) + (h2.y + h3.y);
    }
  }
  for (; e + 4 <= e1; e += 4) {
    int j0 = srcs[e + 0], j1 = srcs[e + 1], j2 = srcs[e + 2], j3 = srcs[e + 3];
    unsigned u0 = xh32[(long)j0 * 16 + lane];
    unsigned u1 = xh32[(long)j1 * 16 + lane];
    unsigned u2 = xh32[(long)j2 * 16 + lane];
    unsigned u3 = xh32[(long)j3 * 16 + lane];
    v2f l0 = __builtin_amdgcn_cvt_pk_f32_fp8((int)u0, false);
    v2f h0 = __builtin_amdgcn_cvt_pk_f32_fp8((int)u0, true);
    v2f l1 = __builtin_amdgcn_cvt_pk_f32_fp8((int)u1, false);
    v2f h1 = __builtin_amdgcn_cvt_pk_f32_fp8((int)u1, true);
    v2f l2 = __builtin_amdgcn_cvt_pk_f32_fp8((int)u2, false);
    v2f h2 = __builtin_amdgcn_cvt_pk_f32_fp8((int)u2, true);
    v2f l3 = __builtin_amdgcn_cvt_pk_f32_fp8((int)u3, false);
    v2f h3 = __builtin_amdgcn_cvt_pk_f32_fp8((int)u3, true);
    s0 += (l0.x + l1.x) + (l2.x + l3.x);
    s1 += (l0.y + l1.y) + (l2.y + l3.y);
    s2 += (h0.x + h1.x) + (h2.x + h3.x);
    s3 += (h0.y + h1.y) + (h2.y + h3.y);
  }
  for (; e < e1; e++) {
    unsigned u = xh32[(long)srcs[e] * 16 + lane];
    v2f lo = __builtin_amdgcn_cvt_pk_f32_fp8((int)u, false);
    v2f hi = __builtin_amdgcn_cvt_pk_f32_fp8((int)u, true);
    s0 += lo.x; s1 += lo.y; s2 += hi.x; s3 += hi.y;
  }
  *(float4*)&agg[(long)i * D + lane * 4] = make_float4(s0, s1, s2, s3);
}

// ---- fused layer (64 rows/block): z = (leaky(Xeff@W1+b1))@W2+b2 + stats ----
__global__ __launch_bounds__(256) void layer_kernel(
    const float* __restrict__ X,
    const float* __restrict__ AGG,
    const unsigned* __restrict__ CNT8, const float* __restrict__ EMB,
    const int* __restrict__ deg, float* __restrict__ Z0,
    const float* __restrict__ epsv, int l,
    const float* __restrict__ W1, const float* __restrict__ b1,
    const float* __restrict__ W2, const float* __restrict__ b2,
    float* __restrict__ Z, float* __restrict__ spread)
{
  __shared__ float Ws[64][64];
  __shared__ float XsT[64][64];
  int t = threadIdx.x;
  int i0 = blockIdx.x * 64;
  float alpha = 1.0f + epsv[l];
  int c0 = (t & 15) * 4;
  int r0 = (t >> 4) * 4;
  int wr = t >> 4;
  int wc = (t & 15) * 4;
  int row = t & 63;
  int gi_row = i0 + row;
  int gis_row = (gi_row < NN) ? gi_row : NN - 1;
  int kb = (t >> 6) * 16;

  if (CNT8) {
    #pragma unroll
    for (int j = 0; j < 4; j++)
      *(float4*)&Ws[wr + 16 * j][wc] = *(const float4*)&EMB[(long)(wr + 16 * j) * D + wc];
    #pragma unroll
    for (int j = 0; j < 4; j++) {
      unsigned u = CNT8[(long)gis_row * 16 + (kb >> 2) + j];
      int k = kb + 4 * j;
      XsT[k + 0][row] = (float)(u & 255);
      XsT[k + 1][row] = (float)((u >> 8) & 255);
      XsT[k + 2][row] = (float)((u >> 16) & 255);
      XsT[k + 3][row] = (float)(u >> 24);
    }
    __syncthreads();
    float4 acc[4];
    #pragma unroll
    for (int r = 0; r < 4; r++) acc[r] = make_float4(0.f, 0.f, 0.f, 0.f);
    #pragma unroll 8
    for (int k = 0; k < 64; k++) {
      float4 w4 = *(const float4*)&Ws[k][c0];
      float4 x4 = *(const float4*)&XsT[k][r0];
      FMA4(acc[0], x4.x, w4); FMA4(acc[1], x4.y, w4);
      FMA4(acc[2], x4.z, w4); FMA4(acc[3], x4.w, w4);
    }
    __syncthreads();
    #pragma unroll
    for (int r = 0; r < 4; r++) {
      int gi = i0 + r0 + r;
      int gis = (gi < NN) ? gi : NN - 1;
      float4 xv = *(const float4*)&EMB[(long)deg[gis] * D + c0];
      if (gi < NN) *(float4*)&Z0[(long)gi * 256 + c0] = xv;
      XsT[c0 + 0][r0 + r] = alpha * xv.x + acc[r].x;
      XsT[c0 + 1][r0 + r] = alpha * xv.y + acc[r].y;
      XsT[c0 + 2][r0 + r] = alpha * xv.z + acc[r].z;
      XsT[c0 + 3][r0 + r] = alpha * xv.w + acc[r].w;
    }
    #pragma unroll
    for (int j = 0; j < 4; j++)
      *(float4*)&Ws[wr + 16 * j][wc] = *(const float4*)&W1[(long)(wr + 16 * j) * D + wc];
    __syncthreads();
  } else {
    #pragma unroll
    for (int j = 0; j < 4; j++)
      *(float4*)&Ws[wr + 16 * j][wc] = *(const float4*)&W1[(long)(wr + 16 * j) * D + wc];
    #pragma unroll
    for (int j = 0; j < 4; j++) {
      int k = kb + 4 * j;
      float4 xv = *(const float4*)&X[(long)gis_row * 256 + k];
      float4 a4 = *(const float4*)&AGG[(long)gis_row * D + k];
      XsT[k + 0][row] = alpha * xv.x + a4.x;
      XsT[k + 1][row] = alpha * xv.y + a4.y;
      XsT[k + 2][row] = alpha * xv.z + a4.z;
      XsT[k + 3][row] = alpha * xv.w + a4.w;
    }
    __syncthreads();
  }

  float4 h[4];
  {
    float4 b4 = *(const float4*)&b1[c0];
    #pragma unroll
    for (int r = 0; r < 4; r++) h[r] = b4;
  }
  #pragma unroll 8
  for (int k = 0; k < 64; k++) {
    float4 w4 = *(const float4*)&Ws[k][c0];
    float4 x4 = *(const float4*)&XsT[k][r0];
    FMA4(h[0], x4.x, w4); FMA4(h[1], x4.y, w4);
    FMA4(h[2], x4.z, w4); FMA4(h[3], x4.w, w4);
  }
  #pragma unroll
  for (int r = 0; r < 4; r++) {
    h[r].x = (h[r].x >= 0.0f) ? h[r].x : 0.01f * h[r].x;
    h[r].y = (h[r].y >= 0.0f) ? h[r].y : 0.01f * h[r].y;
    h[r].z = (h[r].z >= 0.0f) ? h[r].z : 0.01f * h[r].z;
    h[r].w = (h[r].w >= 0.0f) ? h[r].w : 0.01f * h[r].w;
  }
  __syncthreads();
  #pragma unroll
  for (int r = 0; r < 4; r++) {
    XsT[c0 + 0][r0 + r] = h[r].x;
    XsT[c0 + 1][r0 + r] = h[r].y;
    XsT[c0 + 2][r0 + r] = h[r].z;
    XsT[c0 + 3][r0 + r] = h[r].w;
  }
  #pragma unroll
  for (int j = 0; j < 4; j++)
    *(float4*)&Ws[wr + 16 * j][wc] = *(const float4*)&W2[(long)(wr + 16 * j) * D + wc];
  __syncthreads();

  float4 z[4];
  {
    float4 b4 = *(const float4*)&b2[c0];
    #pragma unroll
    for (int r = 0; r < 4; r++) z[r] = b4;
  }
  #pragma unroll 8
  for (int k = 0; k < 64; k++) {
    float4 w4 = *(const float4*)&Ws[k][c0];
    float4 x4 = *(const float4*)&XsT[k][r0];
    FMA4(z[0], x4.x, w4); FMA4(z[1], x4.y, w4);
    FMA4(z[2], x4.z, w4); FMA4(z[3], x4.w, w4);
  }
  #pragma unroll
  for (int r = 0; r < 4; r++) {
    int gi = i0 + r0 + r;
    if (gi < NN) *(float4*)&Z[(long)gi * 256 + c0] = z[r];
  }

  float s[4] = {0, 0, 0, 0}, sq[4] = {0, 0, 0, 0};
  #pragma unroll
  for (int r = 0; r < 4; r++) {
    if (i0 + r0 + r < NN) {
      s[0] += z[r].x; sq[0] += z[r].x * z[r].x;
      s[1] += z[r].y; sq[1] += z[r].y * z[r].y;
      s[2] += z[r].z; sq[2] += z[r].z * z[r].z;
      s[3] += z[r].w; sq[3] += z[r].w * z[r].w;
    }
  }
  __syncthreads();
  float* red = &XsT[0][0];
  int grp = t >> 4;
  #pragma unroll
  for (int j = 0; j < 4; j++) {
    red[grp * 64 + c0 + j] = s[j];
    red[1024 + grp * 64 + c0 + j] = sq[j];
  }
  __syncthreads();
  if (t < 64) {
    float a = 0.0f, b = 0.0f;
    #pragma unroll
    for (int g = 0; g < 16; g++) {
      a += red[g * 64 + t];
      b += red[1024 + g * 64 + t];
    }
    int slot = blockIdx.x & (SPREAD - 1);
    atomicAdd(&spread[slot * 128 + t], a);
    atomicAdd(&spread[slot * 128 + 64 + t], b);
  }
}

// ---- fc1 (64 rows/block): K=256 gemm + BN partial stats ----
__global__ __launch_bounds__(256) void fc1_kernel(
    const float* __restrict__ X,
    const float* __restrict__ W, const float* __restrict__ bias,
    float* __restrict__ Y, float* __restrict__ spread)
{
  __shared__ float Ws[64][64];
  __shared__ float XsT[64][64];
  int t = threadIdx.x;
  int i0 = blockIdx.x * 64;
  int c0 = (t & 15) * 4;
  int r0 = (t >> 4) * 4;
  int wr = t >> 4;
  int wc = (t & 15) * 4;

  float4 acc[4];
  {
    float4 b4 = *(const float4*)&bias[c0];
    #pragma unroll
    for (int r = 0; r < 4; r++) acc[r] = b4;
  }
  for (int kc = 0; kc < 256; kc += 64) {
    __syncthreads();
    #pragma unroll
    for (int j = 0; j < 4; j++)
      *(float4*)&Ws[wr + 16 * j][wc] = *(const float4*)&W[(long)(kc + wr + 16 * j) * D + wc];
    {
      int row = t & 63;
      int gi = i0 + row;
      int gis = (gi < NN) ? gi : NN - 1;
      int kb = (t >> 6) * 16;
      #pragma unroll
      for (int j = 0; j < 4; j++) {
        int k = kb + 4 * j;
        float4 xv = *(const float4*)&X[(long)gis * 256 + kc + k];
        XsT[k + 0][row] = xv.x;
        XsT[k + 1][row] = xv.y;
        XsT[k + 2][row] = xv.z;
        XsT[k + 3][row] = xv.w;
      }
    }
    __syncthreads();
    #pragma unroll 8
    for (int k = 0; k < 64; k++) {
      float4 w4 = *(const float4*)&Ws[k][c0];
      float4 x4 = *(const float4*)&XsT[k][r0];
      FMA4(acc[0], x4.x, w4); FMA4(acc[1], x4.y, w4);
      FMA4(acc[2], x4.z, w4); FMA4(acc[3], x4.w, w4);
    }
  }
  #pragma unroll
  for (int r = 0; r < 4; r++) {
    int gi = i0 + r0 + r;
    if (gi < NN) *(float4*)&Y[(long)gi * D + c0] = acc[r];
  }
  float s[4] = {0, 0, 0, 0}, sq[4] = {0, 0, 0, 0};
  #pragma unroll
  for (int r = 0; r < 4; r++) {
    if (i0 + r0 + r < NN) {
      s[0] += acc[r].x; sq[0] += acc[r].x * acc[r].x;
      s[1] += acc[r].y; sq[1] += acc[r].y * acc[r].y;
      s[2] += acc[r].z; sq[2] += acc[r].z * acc[r].z;
      s[3] += acc[r].w; sq[3] += acc[r].w * acc[r].w;
    }
  }
  __syncthreads();
  float* red = &XsT[0][0];
  int grp = t >> 4;
  #pragma unroll
  for (int j = 0; j < 4; j++) {
    red[grp * 64 + c0 + j] = s[j];
    red[1024 + grp * 64 + c0 + j] = sq[j];
  }
  __syncthreads();
  if (t < 64) {
    float a = 0.0f, b = 0.0f;
    #pragma unroll
    for (int g = 0; g < 16; g++) {
      a += red[g * 64 + t];
      b += red[1024 + g * 64 + t];
    }
    int slot = blockIdx.x & (SPREAD - 1);
    atomicAdd(&spread[slot * 128 + t], a);
    atomicAdd(&spread[slot * 128 + 64 + t], b);
  }
}

// ---- BN apply + leaky (zcat in place) + fp8 [N][64] mirror; reduces
//      SPREAD slots per block (same g-order -> bitwise identical stats) ----
__global__ __launch_bounds__(256) void bn_apply_kernel(float* __restrict__ Zs,
    const float* __restrict__ spread,
    const float* __restrict__ g, const float* __restrict__ b,
    unsigned short* __restrict__ Outh) {
  __shared__ float st[128];
  int t = threadIdx.x;
  if (t < 128) {
    float a = 0.0f;
    #pragma unroll
    for (int gg = 0; gg < SPREAD; gg++) a += spread[gg * 128 + t];
    st[t] = a;
  }
  __syncthreads();
  int idx = blockIdx.x * 256 + t;   // over NN*32 pairs
  int i = idx >> 5, dp = (idx & 31) * 2;
  if (i >= NN) return;
  float invn = 1.0f / (float)NN;
  float v0, v1;
  {
    float mu = st[dp] * invn;
    float var = fmaxf(st[64 + dp] * invn - mu * mu, 0.0f);
    float sc = g[dp] * rsqrtf(var + BN_EPS);
    v0 = sc * (Zs[(long)i * 256 + dp] - mu) + b[dp];
    v0 = (v0 >= 0.0f) ? v0 : 0.01f * v0;
  }
  {
    float mu = st[dp + 1] * invn;
    float var = fmaxf(st[64 + dp + 1] * invn - mu * mu, 0.0f);
    float sc = g[dp + 1] * rsqrtf(var + BN_EPS);
    v1 = sc * (Zs[(long)i * 256 + dp + 1] - mu) + b[dp + 1];
    v1 = (v1 >= 0.0f) ? v1 : 0.01f * v1;
  }
  Zs[(long)i * 256 + dp]     = v0;
  Zs[(long)i * 256 + dp + 1] = v1;
  if (Outh) {
    int packed = __builtin_amdgcn_cvt_pk_fp8_f32(v0, v1, 0, false);
    Outh[(long)i * 32 + (dp >> 1)] = (unsigned short)packed;
  }
}

// ---- fused fc BN-apply + fc2 dot + sigmoid (reduces SPREAD per block) ----
__global__ __launch_bounds__(256) void fc2bn_kernel(const float* __restrict__ H,
    const float* __restrict__ spread,
    const float* __restrict__ g, const float* __restrict__ b,
    const float* __restrict__ W2, const float* __restrict__ b2,
    float* __restrict__ out) {
  __shared__ float st[128];
  int tid = threadIdx.x;
  if (tid < 128) {
    float a = 0.0f;
    #pragma unroll
    for (int gg = 0; gg < SPREAD; gg++) a += spread[gg * 128 + tid];
    st[tid] = a;
  }
  __syncthreads();
  int k = tid & 63, q = tid >> 6;
  int i = blockIdx.x * 4 + q;
  float invn = 1.0f / (float)NN;
  float mu = st[k] * invn;
  float var = fmaxf(st[64 + k] * invn - mu * mu, 0.0f);
  float sc = g[k] * rsqrtf(var + BN_EPS);
  float v = 0.0f;
  if (i < NN) {
    float hv = sc * (H[(long)i * D + k] - mu) + b[k];
    hv = (hv >= 0.0f) ? hv : 0.01f * hv;
    v = hv * W2[k];
  }
  #pragma unroll
  for (int off = 32; off > 0; off >>= 1)
    v += __shfl_down(v, off);
  if (k == 0 && i < NN) {
    float x = v + b2[0];
    out[i] = 1.0f / (1.0f + __expf(-x));
  }
}

extern "C" void kernel_launch(void* const* d_in, const int* in_sizes, int n_in,
                              void* d_out, int out_size, void* d_ws, size_t ws_size,
                              hipStream_t stream) {
  const int*   node_deg   = (const int*)d_in[0];
  const int*   edge_index = (const int*)d_in[1];
  const float* embedw     = (const float*)d_in[2];
  const float* eps        = (const float*)d_in[3];
  const float* W1         = (const float*)d_in[4];
  const float* b1         = (const float*)d_in[5];
  const float* W2         = (const float*)d_in[6];
  const float* b2         = (const float*)d_in[7];
  const float* bn_g       = (const float*)d_in[8];
  const float* bn_b       = (const float*)d_in[9];
  const float* fc_W1      = (const float*)d_in[10];
  const float* fc_b1      = (const float*)d_in[11];
  const float* fc_bn_g    = (const float*)d_in[12];
  const float* fc_bn_b    = (const float*)d_in[13];
  const float* fc_W2      = (const float*)d_in[14];
  const float* fc_b2      = (const float*)d_in[15];

  float* zcat   = (float*)d_ws;                 // [N,256]
  float* agg    = zcat + (long)NN * 256;        // [N,64]
  float* statsS = agg + (long)NN * D;           // 4 * SPREAD*128
  float* statsF = statsS + 4 * SPREAD * 128;    // layout keep
  int*   csroff = (int*)(statsF + 512);         // [NN+1]
  int*   bsum   = csroff + NN + 1;              // [512]
  int*   csrsrc = bsum + 512;                   // [NE]
  int*   rec    = csrsrc + NE;                  // [NE]
  int*   S      = rec + NE;                     // [NP*392]
  unsigned* cnt8 = (unsigned*)(S + NP * 392);   // [N,16] u32
  unsigned short* xh = (unsigned short*)rec;    // fp8 mirror [N][64] overlays rec

  const int rowBlocks   = NN / 4;                 // 25000
  const int layerBlocks = (NN + 63) / 64;         // 1563
  const int aggBlocks   = NN / 16;                // 6250
  const int bnBlocks    = (NN * 32 + 255) / 256;  // 12500

  bucket_kernel<<<NP, 256, 0, stream>>>(edge_index, node_deg, rec, S);
  bucketsum_kernel<<<NB, 256, 0, stream>>>(S, bsum);
  scan2_kernel<<<1, 512, 0, stream>>>(bsum);
  sort_kernel<<<NB, 512, 0, stream>>>(rec, S, bsum, csroff, csrsrc, cnt8);

  hipMemsetAsync(statsS, 0, (size_t)(4 * SPREAD * 128) * sizeof(float), stream);

  for (int l = 0; l < 3; ++l) {
    if (l > 0)
      agg_kernel<<<aggBlocks, 256, 0, stream>>>(csroff, csrsrc,
          (const unsigned*)xh, agg);
    layer_kernel<<<layerBlocks, 256, 0, stream>>>(zcat + l * D,
        (l == 0) ? nullptr : agg,
        (l == 0) ? cnt8 : nullptr, embedw, node_deg, zcat,
        eps, l,
        W1 + (long)l * D * D, b1 + (long)l * D,
        W2 + (long)l * D * D, b2 + (long)l * D,
        zcat + (l + 1) * D, statsS + (long)l * SPREAD * 128);
    bn_apply_kernel<<<bnBlocks, 256, 0, stream>>>(zcat + (l + 1) * D,
        statsS + (long)l * SPREAD * 128,
        bn_g + (long)l * D, bn_b + (long)l * D,
        (l < 2) ? xh : nullptr);
  }

  fc1_kernel<<<layerBlocks, 256, 0, stream>>>(zcat, fc_W1, fc_b1, agg,
      statsS + 3L * SPREAD * 128);
  fc2bn_kernel<<<rowBlocks, 256, 0, stream>>>(agg, statsS + 3L * SPREAD * 128,
      fc_bn_g, fc_bn_b, fc_W2, fc_b2, (float*)d_out);
}

// Round 20
// 478.575 us; speedup vs baseline: 1.1455x; 1.0647x over previous
//
#include <hip/hip_runtime.h>
#include <hip/hip_bf16.h>

#define NN 100000
#define NE 3200000
#define D 64
#define BN_EPS 1e-5f

#define NP 512       // producer blocks
#define CHUNK 6250   // edges per producer (512*6250 = 3.2M exactly)
#define NB 391       // dst buckets of 256 nodes (391*256 = 100096 >= NN)
#define SPREAD 16    // stats contention spread

typedef float v2f __attribute__((ext_vector_type(2)));

#define FMA4(accr, xs, w4) \
  accr.x += (xs) * (w4).x; accr.y += (xs) * (w4).y; \
  accr.z += (xs) * (w4).z; accr.w += (xs) * (w4).w;

// ---- precompute: block 0: E1 = embed[0:64] @ W1_0; block 1: T = embed[0:64] @ fcW1[0:64] ----
__global__ __launch_bounds__(256) void precompute_kernel(
    const float* __restrict__ emb, const float* __restrict__ W1_0,
    const float* __restrict__ fcW1, float* __restrict__ E1,
    float* __restrict__ T) {
  __shared__ float A[64][64];
  __shared__ float B[64][64];
  int t = threadIdx.x;
  const float* W = (blockIdx.x == 0) ? W1_0 : fcW1;
  float* O = (blockIdx.x == 0) ? E1 : T;
  int wr = t >> 4, wc = (t & 15) * 4;
  #pragma unroll
  for (int j = 0; j < 4; j++) {
    *(float4*)&A[wr + 16 * j][wc] = *(const float4*)&emb[(long)(wr + 16 * j) * D + wc];
    *(float4*)&B[wr + 16 * j][wc] = *(const float4*)&W[(long)(wr + 16 * j) * D + wc];
  }
  __syncthreads();
  int c0 = (t & 15) * 4, r0 = (t >> 4) * 4;
  float4 acc[4];
  #pragma unroll
  for (int r = 0; r < 4; r++) acc[r] = make_float4(0.f, 0.f, 0.f, 0.f);
  for (int k = 0; k < 64; k++) {
    float4 w4 = *(const float4*)&B[k][c0];
    FMA4(acc[0], A[r0 + 0][k], w4); FMA4(acc[1], A[r0 + 1][k], w4);
    FMA4(acc[2], A[r0 + 2][k], w4); FMA4(acc[3], A[r0 + 3][k], w4);
  }
  #pragma unroll
  for (int r = 0; r < 4; r++)
    *(float4*)&O[(long)(r0 + r) * D + c0] = acc[r];
}

// ---- producer: bucket edges into private per-block regions.
//      rec = src | dstLocal<<17 | deg[src]<<25; 4-edge ILP batching. ----
__global__ __launch_bounds__(256) void bucket_kernel(const int* __restrict__ ei,
    const int* __restrict__ deg, int* __restrict__ rec, int* __restrict__ S) {
  __shared__ int cntL[392];
  __shared__ int curL[392];
  __shared__ int scanbuf[256];
  int t = threadIdx.x;
  int p = blockIdx.x;
  int e0 = p * CHUNK;
  cntL[t] = 0;
  if (t < 136) cntL[256 + t] = 0;
  __syncthreads();
  {
    int e = t;
    for (; e + 768 < CHUNK; e += 1024) {
      int d0 = ei[NE + e0 + e];
      int d1 = ei[NE + e0 + e + 256];
      int d2 = ei[NE + e0 + e + 512];
      int d3 = ei[NE + e0 + e + 768];
      atomicAdd(&cntL[(unsigned)d0 >> 8], 1);
      atomicAdd(&cntL[(unsigned)d1 >> 8], 1);
      atomicAdd(&cntL[(unsigned)d2 >> 8], 1);
      atomicAdd(&cntL[(unsigned)d3 >> 8], 1);
    }
    for (; e < CHUNK; e += 256) {
      int dd = ei[NE + e0 + e];
      atomicAdd(&cntL[(unsigned)dd >> 8], 1);
    }
  }
  __syncthreads();
  int a0 = 0, a1 = 0;
  if (t < 196) { a0 = cntL[2 * t]; a1 = cntL[2 * t + 1]; }
  int s = a0 + a1;
  scanbuf[t] = s;
  __syncthreads();
  for (int off = 1; off < 256; off <<= 1) {
    int x = (t >= off) ? scanbuf[t - off] : 0;
    __syncthreads();
    scanbuf[t] += x;
    __syncthreads();
  }
  int ex = scanbuf[t] - s;
  if (t < 196) {
    curL[2 * t]     = ex;
    curL[2 * t + 1] = ex + a0;
    S[p * 392 + 2 * t]     = e0 + ex;
    S[p * 392 + 2 * t + 1] = e0 + ex + a0;
  }
  __syncthreads();
  {
    int e = t;
    for (; e + 768 < CHUNK; e += 1024) {
      int s0 = ei[e0 + e],       d0 = ei[NE + e0 + e];
      int s1 = ei[e0 + e + 256], d1 = ei[NE + e0 + e + 256];
      int s2 = ei[e0 + e + 512], d2 = ei[NE + e0 + e + 512];
      int s3 = ei[e0 + e + 768], d3 = ei[NE + e0 + e + 768];
      int g0 = deg[s0], g1 = deg[s1], g2 = deg[s2], g3 = deg[s3];
      int p0 = atomicAdd(&curL[(unsigned)d0 >> 8], 1);
      int p1 = atomicAdd(&curL[(unsigned)d1 >> 8], 1);
      int p2 = atomicAdd(&curL[(unsigned)d2 >> 8], 1);
      int p3 = atomicAdd(&curL[(unsigned)d3 >> 8], 1);
      rec[e0 + p0] = s0 | ((d0 & 255) << 17) | (g0 << 25);
      rec[e0 + p1] = s1 | ((d1 & 255) << 17) | (g1 << 25);
      rec[e0 + p2] = s2 | ((d2 & 255) << 17) | (g2 << 25);
      rec[e0 + p3] = s3 | ((d3 & 255) << 17) | (g3 << 25);
    }
    for (; e < CHUNK; e += 256) {
      int ss = ei[e0 + e];
      int dd = ei[NE + e0 + e];
      int dg = deg[ss];
      int b = (unsigned)dd >> 8;
      int pos = atomicAdd(&curL[b], 1);
      rec[e0 + pos] = ss | ((dd & 255) << 17) | (dg << 25);
    }
  }
}

// ---- bucket totals ----
__global__ __launch_bounds__(256) void bucketsum_kernel(const int* __restrict__ S,
    int* __restrict__ bsum) {
  __shared__ int sh[256];
  int B = blockIdx.x;
  int t = threadIdx.x;
  int c = 0;
  for (int p = t; p < NP; p += 256)
    c += S[p * 392 + B + 1] - S[p * 392 + B];
  sh[t] = c;
  __syncthreads();
  for (int o = 128; o > 0; o >>= 1) {
    if (t < o) sh[t] += sh[t + o];
    __syncthreads();
  }
  if (t == 0) bsum[B] = sh[0];
}

// ---- exclusive scan of 391 bucket totals ----
__global__ __launch_bounds__(512) void scan2_kernel(int* __restrict__ bsum) {
  __shared__ int sh[512];
  int t = threadIdx.x;
  int v = (t < NB) ? bsum[t] : 0;
  sh[t] = v;
  __syncthreads();
  for (int o = 1; o < 512; o <<= 1) {
    int x = (t >= o) ? sh[t - o] : 0;
    __syncthreads();
    sh[t] += x;
    __syncthreads();
  }
  if (t < NB) bsum[t] = sh[t] - v;
}

// ---- sorter + neighbor-degree histogram (u16-packed, LDS 33 KB) ----
__global__ __launch_bounds__(512) void sort_kernel(const int* __restrict__ rec,
    const int* __restrict__ S, const int* __restrict__ bsum,
    int* __restrict__ csroff, int* __restrict__ csrsrc,
    unsigned* __restrict__ cnt8) {
  __shared__ int cntL[256];
  __shared__ int curL[256];
  __shared__ unsigned hist[256 * 33];
  int t = threadIdx.x;
  int B = blockIdx.x;
  if (t < 256) cntL[t] = 0;
  for (int k = t; k < 256 * 33; k += 512) hist[k] = 0;
  __syncthreads();
  int lane = t & 15;
  int g = t >> 4;
  for (int p = g; p < NP; p += 32) {
    int s0 = S[p * 392 + B], s1 = S[p * 392 + B + 1];
    for (int e = s0 + lane; e < s1; e += 16) {
      int r = rec[e];
      int dl = (r >> 17) & 255;
      int dg = (unsigned)r >> 25;
      atomicAdd(&cntL[dl], 1);
      atomicAdd(&hist[dl * 33 + (dg >> 1)], (dg & 1) ? 0x10000u : 1u);
    }
  }
  __syncthreads();
  int v = 0;
  if (t < 256) { v = cntL[t]; curL[t] = v; }
  __syncthreads();
  for (int o = 1; o < 256; o <<= 1) {
    int x = 0;
    if (t < 256 && t >= o) x = curL[t - o];
    __syncthreads();
    if (t < 256) curL[t] += x;
    __syncthreads();
  }
  int b0 = bsum[B];
  if (t < 256) {
    int excl = curL[t] - v;
    int node = B * 256 + t;
    if (node <= NN) csroff[node] = b0 + excl;
  }
  __syncthreads();
  if (t < 256) curL[t] = b0 + (curL[t] - v);
  if (t < 256) {
    int node = B * 256 + t;
    if (node < NN) {
      #pragma unroll
      for (int j = 0; j < 16; j++) {
        unsigned p0 = hist[t * 33 + 2 * j];
        unsigned p1 = hist[t * 33 + 2 * j + 1];
        unsigned p = (p0 & 255) | (((p0 >> 16) & 255) << 8)
                   | ((p1 & 255) << 16) | (((p1 >> 16) & 255) << 24);
        cnt8[(long)node * 16 + j] = p;
      }
    }
  }
  __syncthreads();
  for (int p = g; p < NP; p += 32) {
    int s0 = S[p * 392 + B], s1 = S[p * 392 + B + 1];
    for (int e = s0 + lane; e < s1; e += 16) {
      int r = rec[e];
      int pos = atomicAdd(&curL[(r >> 17) & 255], 1);
      csrsrc[pos] = r & 0x1FFFF;
    }
  }
}

// ---- aggregation (layers 1,2): fp8 e4m3 [N][64], one line touch/edge.
//      8 loads in flight; FP adds in the original 4-batch order. ----
__global__ __launch_bounds__(256) void agg_kernel(const int* __restrict__ off,
    const int* __restrict__ srcs, const unsigned* __restrict__ xh32,
    float* __restrict__ agg) {
  int t = threadIdx.x;
  int lane = t & 15;
  int g = t >> 4;
  int i = blockIdx.x * 16 + g;
  int e0 = off[i], e1 = off[i + 1];
  float s0 = 0.f, s1 = 0.f, s2 = 0.f, s3 = 0.f;
  int e = e0;
  for (; e + 8 <= e1; e += 8) {
    int j0 = srcs[e + 0], j1 = srcs[e + 1], j2 = srcs[e + 2], j3 = srcs[e + 3];
    int j4 = srcs[e + 4], j5 = srcs[e + 5], j6 = srcs[e + 6], j7 = srcs[e + 7];
    unsigned u0 = xh32[(long)j0 * 16 + lane];
    unsigned u1 = xh32[(long)j1 * 16 + lane];
    unsigned u2 = xh32[(long)j2 * 16 + lane];
    unsigned u3 = xh32[(long)j3 * 16 + lane];
    unsigned u4 = xh32[(long)j4 * 16 + lane];
    unsigned u5 = xh32[(long)j5 * 16 + lane];
    unsigned u6 = xh32[(long)j6 * 16 + lane];
    unsigned u7 = xh32[(long)j7 * 16 + lane];
    {
      v2f l0 = __builtin_amdgcn_cvt_pk_f32_fp8((int)u0, false);
      v2f h0 = __builtin_amdgcn_cvt_pk_f32_fp8((int)u0, true);
      v2f l1 = __builtin_amdgcn_cvt_pk_f32_fp8((int)u1, false);
      v2f h1 = __builtin_amdgcn_cvt_pk_f32_fp8((int)u1, true);
      v2f l2 = __builtin_amdgcn_cvt_pk_f32_fp8((int)u2, false);
      v2f h2 = __builtin_amdgcn_cvt_pk_f32_fp8((int)u2, true);
      v2f l3 = __builtin_amdgcn_cvt_pk_f32_fp8((int)u3, false);
      v2f h3 = __builtin_amdgcn_cvt_pk_f32_fp8((int)u3, true);
      s0 += (l0.x + l1.x) + (l2.x + l3.x);
      s1 += (l0.y + l1.y) + (l2.y + l3.y);
      s2 += (h0.x + h1.x) + (h2.x + h3.x);
      s3 += (h0.y + h1.y) + (h2.y + h3.y);
    }
    {
      v2f l0 = __builtin_amdgcn_cvt_pk_f32_fp8((int)u4, false);
      v2f h0 = __builtin_amdgcn_cvt_pk_f32_fp8((int)u4, true);
      v2f l1 = __builtin_amdgcn_cvt_pk_f32_fp8((int)u5, false);
      v2f h1 = __builtin_amdgcn_cvt_pk_f32_fp8((int)u5, true);
      v2f l2 = __builtin_amdgcn_cvt_pk_f32_fp8((int)u6, false);
      v2f h2 = __builtin_amdgcn_cvt_pk_f32_fp8((int)u6, true);
      v2f l3 = __builtin_amdgcn_cvt_pk_f32_fp8((int)u7, false);
      v2f h3 = __builtin_amdgcn_cvt_pk_f32_fp8((int)u7, true);
      s0 += (l0.x + l1.x) + (l2.x + l3.x);
      s1 += (l0.y + l1.y) + (l2.y + l3.y);
      s2 += (h0.x + h1.x) + (h2.x + h3.x);
      s3 += (h0.y + h1.y) + (h2.y + h3.y);
    }
  }
  for (; e + 4 <= e1; e += 4) {
    int j0 = srcs[e + 0], j1 = srcs[e + 1], j2 = srcs[e + 2], j3 = srcs[e + 3];
    unsigned u0 = xh32[(long)j0 * 16 + lane];
    unsigned u1 = xh32[(long)j1 * 16 + lane];
    unsigned u2 = xh32[(long)j2 * 16 + lane];
    unsigned u3 = xh32[(long)j3 * 16 + lane];
    v2f l0 = __builtin_amdgcn_cvt_pk_f32_fp8((int)u0, false);
    v2f h0 = __builtin_amdgcn_cvt_pk_f32_fp8((int)u0, true);
    v2f l1 = __builtin_amdgcn_cvt_pk_f32_fp8((int)u1, false);
    v2f h1 = __builtin_amdgcn_cvt_pk_f32_fp8((int)u1, true);
    v2f l2 = __builtin_amdgcn_cvt_pk_f32_fp8((int)u2, false);
    v2f h2 = __builtin_amdgcn_cvt_pk_f32_fp8((int)u2, true);
    v2f l3 = __builtin_amdgcn_cvt_pk_f32_fp8((int)u3, false);
    v2f h3 = __builtin_amdgcn_cvt_pk_f32_fp8((int)u3, true);
    s0 += (l0.x + l1.x) + (l2.x + l3.x);
    s1 += (l0.y + l1.y) + (l2.y + l3.y);
    s2 += (h0.x + h1.x) + (h2.x + h3.x);
    s3 += (h0.y + h1.y) + (h2.y + h3.y);
  }
  for (; e < e1; e++) {
    unsigned u = xh32[(long)srcs[e] * 16 + lane];
    v2f lo = __builtin_amdgcn_cvt_pk_f32_fp8((int)u, false);
    v2f hi = __builtin_amdgcn_cvt_pk_f32_fp8((int)u, true);
    s0 += lo.x; s1 += lo.y; s2 += hi.x; s3 += hi.y;
  }
  *(float4*)&agg[(long)i * D + lane * 4] = make_float4(s0, s1, s2, s3);
}

// ---- fused layer (64 rows/block). l==0: h = leaky(b1 + alpha*E1[deg] +
//      cnt8@E1) — E1 = embed@W1 precomputed (one gemm pass, no zcat0 write).
//      l>0: h = leaky((alpha*x+agg)@W1 + b1). Then z = h@W2+b2 + stats. ----
__global__ __launch_bounds__(256) void layer_kernel(
    const float* __restrict__ X,
    const float* __restrict__ AGG,
    const unsigned* __restrict__ CNT8, const float* __restrict__ E1,
    const int* __restrict__ deg,
    const float* __restrict__ epsv, int l,
    const float* __restrict__ W1, const float* __restrict__ b1,
    const float* __restrict__ W2, const float* __restrict__ b2,
    float* __restrict__ Z, float* __restrict__ spread)
{
  __shared__ float Ws[64][64];
  __shared__ float XsT[64][64];
  int t = threadIdx.x;
  int i0 = blockIdx.x * 64;
  float alpha = 1.0f + epsv[l];
  int c0 = (t & 15) * 4;
  int r0 = (t >> 4) * 4;
  int wr = t >> 4;
  int wc = (t & 15) * 4;
  int row = t & 63;
  int gi_row = i0 + row;
  int gis_row = (gi_row < NN) ? gi_row : NN - 1;
  int kb = (t >> 6) * 16;

  float4 h[4];
  if (CNT8) {
    // stage E1 -> Ws, counts -> XsT
    #pragma unroll
    for (int j = 0; j < 4; j++)
      *(float4*)&Ws[wr + 16 * j][wc] = *(const float4*)&E1[(long)(wr + 16 * j) * D + wc];
    #pragma unroll
    for (int j = 0; j < 4; j++) {
      unsigned u = CNT8[(long)gis_row * 16 + (kb >> 2) + j];
      int k = kb + 4 * j;
      XsT[k + 0][row] = (float)(u & 255);
      XsT[k + 1][row] = (float)((u >> 8) & 255);
      XsT[k + 2][row] = (float)((u >> 16) & 255);
      XsT[k + 3][row] = (float)(u >> 24);
    }
    __syncthreads();
    float4 acc[4];
    #pragma unroll
    for (int r = 0; r < 4; r++) acc[r] = make_float4(0.f, 0.f, 0.f, 0.f);
    #pragma unroll 8
    for (int k = 0; k < 64; k++) {
      float4 w4 = *(const float4*)&Ws[k][c0];
      float4 x4 = *(const float4*)&XsT[k][r0];
      FMA4(acc[0], x4.x, w4); FMA4(acc[1], x4.y, w4);
      FMA4(acc[2], x4.z, w4); FMA4(acc[3], x4.w, w4);
    }
    // h = b1 + alpha*E1[deg[row_r]] + acc   (E1 row gather from LDS)
    float4 b4 = *(const float4*)&b1[c0];
    #pragma unroll
    for (int r = 0; r < 4; r++) {
      int gi = i0 + r0 + r;
      int gis = (gi < NN) ? gi : NN - 1;
      int dg = deg[gis];
      float4 e4 = *(const float4*)&Ws[dg][c0];
      h[r].x = b4.x + alpha * e4.x + acc[r].x;
      h[r].y = b4.y + alpha * e4.y + acc[r].y;
      h[r].z = b4.z + alpha * e4.z + acc[r].z;
      h[r].w = b4.w + alpha * e4.w + acc[r].w;
    }
  } else {
    #pragma unroll
    for (int j = 0; j < 4; j++)
      *(float4*)&Ws[wr + 16 * j][wc] = *(const float4*)&W1[(long)(wr + 16 * j) * D + wc];
    #pragma unroll
    for (int j = 0; j < 4; j++) {
      int k = kb + 4 * j;
      float4 xv = *(const float4*)&X[(long)gis_row * 256 + k];
      float4 a4 = *(const float4*)&AGG[(long)gis_row * D + k];
      XsT[k + 0][row] = alpha * xv.x + a4.x;
      XsT[k + 1][row] = alpha * xv.y + a4.y;
      XsT[k + 2][row] = alpha * xv.z + a4.z;
      XsT[k + 3][row] = alpha * xv.w + a4.w;
    }
    __syncthreads();
    {
      float4 b4 = *(const float4*)&b1[c0];
      #pragma unroll
      for (int r = 0; r < 4; r++) h[r] = b4;
    }
    #pragma unroll 8
    for (int k = 0; k < 64; k++) {
      float4 w4 = *(const float4*)&Ws[k][c0];
      float4 x4 = *(const float4*)&XsT[k][r0];
      FMA4(h[0], x4.x, w4); FMA4(h[1], x4.y, w4);
      FMA4(h[2], x4.z, w4); FMA4(h[3], x4.w, w4);
    }
  }
  #pragma unroll
  for (int r = 0; r < 4; r++) {
    h[r].x = (h[r].x >= 0.0f) ? h[r].x : 0.01f * h[r].x;
    h[r].y = (h[r].y >= 0.0f) ? h[r].y : 0.01f * h[r].y;
    h[r].z = (h[r].z >= 0.0f) ? h[r].z : 0.01f * h[r].z;
    h[r].w = (h[r].w >= 0.0f) ? h[r].w : 0.01f * h[r].w;
  }
  __syncthreads();
  #pragma unroll
  for (int r = 0; r < 4; r++) {
    XsT[c0 + 0][r0 + r] = h[r].x;
    XsT[c0 + 1][r0 + r] = h[r].y;
    XsT[c0 + 2][r0 + r] = h[r].z;
    XsT[c0 + 3][r0 + r] = h[r].w;
  }
  #pragma unroll
  for (int j = 0; j < 4; j++)
    *(float4*)&Ws[wr + 16 * j][wc] = *(const float4*)&W2[(long)(wr + 16 * j) * D + wc];
  __syncthreads();

  float4 z[4];
  {
    float4 b4 = *(const float4*)&b2[c0];
    #pragma unroll
    for (int r = 0; r < 4; r++) z[r] = b4;
  }
  #pragma unroll 8
  for (int k = 0; k < 64; k++) {
    float4 w4 = *(const float4*)&Ws[k][c0];
    float4 x4 = *(const float4*)&XsT[k][r0];
    FMA4(z[0], x4.x, w4); FMA4(z[1], x4.y, w4);
    FMA4(z[2], x4.z, w4); FMA4(z[3], x4.w, w4);
  }
  #pragma unroll
  for (int r = 0; r < 4; r++) {
    int gi = i0 + r0 + r;
    if (gi < NN) *(float4*)&Z[(long)gi * 256 + c0] = z[r];
  }

  float s[4] = {0, 0, 0, 0}, sq[4] = {0, 0, 0, 0};
  #pragma unroll
  for (int r = 0; r < 4; r++) {
    if (i0 + r0 + r < NN) {
      s[0] += z[r].x; sq[0] += z[r].x * z[r].x;
      s[1] += z[r].y; sq[1] += z[r].y * z[r].y;
      s[2] += z[r].z; sq[2] += z[r].z * z[r].z;
      s[3] += z[r].w; sq[3] += z[r].w * z[r].w;
    }
  }
  __syncthreads();
  float* red = &XsT[0][0];
  int grp = t >> 4;
  #pragma unroll
  for (int j = 0; j < 4; j++) {
    red[grp * 64 + c0 + j] = s[j];
    red[1024 + grp * 64 + c0 + j] = sq[j];
  }
  __syncthreads();
  if (t < 64) {
    float a = 0.0f, b = 0.0f;
    #pragma unroll
    for (int g = 0; g < 16; g++) {
      a += red[g * 64 + t];
      b += red[1024 + g * 64 + t];
    }
    int slot = blockIdx.x & (SPREAD - 1);
    atomicAdd(&spread[slot * 128 + t], a);
    atomicAdd(&spread[slot * 128 + 64 + t], b);
  }
}

// ---- fc1 (64 rows/block): K=192 gemm (kc=64..256) + folded slice-0 via
//      T[deg] (T = embed@fcW1[0:64], 16 KB L2-resident) + BN partial stats ----
__global__ __launch_bounds__(256) void fc1_kernel(
    const float* __restrict__ X, const int* __restrict__ deg,
    const float* __restrict__ T,
    const float* __restrict__ W, const float* __restrict__ bias,
    float* __restrict__ Y, float* __restrict__ spread)
{
  __shared__ float Ws[64][64];
  __shared__ float XsT[64][64];
  int t = threadIdx.x;
  int i0 = blockIdx.x * 64;
  int c0 = (t & 15) * 4;
  int r0 = (t >> 4) * 4;
  int wr = t >> 4;
  int wc = (t & 15) * 4;

  float4 acc[4];
  {
    float4 b4 = *(const float4*)&bias[c0];
    #pragma unroll
    for (int r = 0; r < 4; r++) {
      int gi = i0 + r0 + r;
      int gis = (gi < NN) ? gi : NN - 1;
      int dg = deg[gis];
      float4 t4 = *(const float4*)&T[(long)dg * D + c0];
      acc[r].x = b4.x + t4.x;
      acc[r].y = b4.y + t4.y;
      acc[r].z = b4.z + t4.z;
      acc[r].w = b4.w + t4.w;
    }
  }
  for (int kc = 64; kc < 256; kc += 64) {
    __syncthreads();
    #pragma unroll
    for (int j = 0; j < 4; j++)
      *(float4*)&Ws[wr + 16 * j][wc] = *(const float4*)&W[(long)(kc + wr + 16 * j) * D + wc];
    {
      int row = t & 63;
      int gi = i0 + row;
      int gis = (gi < NN) ? gi : NN - 1;
      int kb = (t >> 6) * 16;
      #pragma unroll
      for (int j = 0; j < 4; j++) {
        int k = kb + 4 * j;
        float4 xv = *(const float4*)&X[(long)gis * 256 + kc + k];
        XsT[k + 0][row] = xv.x;
        XsT[k + 1][row] = xv.y;
        XsT[k + 2][row] = xv.z;
        XsT[k + 3][row] = xv.w;
      }
    }
    __syncthreads();
    #pragma unroll 8
    for (int k = 0; k < 64; k++) {
      float4 w4 = *(const float4*)&Ws[k][c0];
      float4 x4 = *(const float4*)&XsT[k][r0];
      FMA4(acc[0], x4.x, w4); FMA4(acc[1], x4.y, w4);
      FMA4(acc[2], x4.z, w4); FMA4(acc[3], x4.w, w4);
    }
  }
  #pragma unroll
  for (int r = 0; r < 4; r++) {
    int gi = i0 + r0 + r;
    if (gi < NN) *(float4*)&Y[(long)gi * D + c0] = acc[r];
  }
  float s[4] = {0, 0, 0, 0}, sq[4] = {0, 0, 0, 0};
  #pragma unroll
  for (int r = 0; r < 4; r++) {
    if (i0 + r0 + r < NN) {
      s[0] += acc[r].x; sq[0] += acc[r].x * acc[r].x;
      s[1] += acc[r].y; sq[1] += acc[r].y * acc[r].y;
      s[2] += acc[r].z; sq[2] += acc[r].z * acc[r].z;
      s[3] += acc[r].w; sq[3] += acc[r].w * acc[r].w;
    }
  }
  __syncthreads();
  float* red = &XsT[0][0];
  int grp = t >> 4;
  #pragma unroll
  for (int j = 0; j < 4; j++) {
    red[grp * 64 + c0 + j] = s[j];
    red[1024 + grp * 64 + c0 + j] = sq[j];
  }
  __syncthreads();
  if (t < 64) {
    float a = 0.0f, b = 0.0f;
    #pragma unroll
    for (int g = 0; g < 16; g++) {
      a += red[g * 64 + t];
      b += red[1024 + g * 64 + t];
    }
    int slot = blockIdx.x & (SPREAD - 1);
    atomicAdd(&spread[slot * 128 + t], a);
    atomicAdd(&spread[slot * 128 + 64 + t], b);
  }
}

// ---- BN apply + leaky (zcat in place) + fp8 [N][64] mirror; reduces
//      SPREAD slots per block (same g-order -> bitwise identical stats) ----
__global__ __launch_bounds__(256) void bn_apply_kernel(float* __restrict__ Zs,
    const float* __restrict__ spread,
    const float* __restrict__ g, const float* __restrict__ b,
    unsigned short* __restrict__ Outh) {
  __shared__ float st[128];
  int t = threadIdx.x;
  if (t < 128) {
    float a = 0.0f;
    #pragma unroll
    for (int gg = 0; gg < SPREAD; gg++) a += spread[gg * 128 + t];
    st[t] = a;
  }
  __syncthreads();
  int idx = blockIdx.x * 256 + t;   // over NN*32 pairs
  int i = idx >> 5, dp = (idx & 31) * 2;
  if (i >= NN) return;
  float invn = 1.0f / (float)NN;
  float v0, v1;
  {
    float mu = st[dp] * invn;
    float var = fmaxf(st[64 + dp] * invn - mu * mu, 0.0f);
    float sc = g[dp] * rsqrtf(var + BN_EPS);
    v0 = sc * (Zs[(long)i * 256 + dp] - mu) + b[dp];
    v0 = (v0 >= 0.0f) ? v0 : 0.01f * v0;
  }
  {
    float mu = st[dp + 1] * invn;
    float var = fmaxf(st[64 + dp + 1] * invn - mu * mu, 0.0f);
    float sc = g[dp + 1] * rsqrtf(var + BN_EPS);
    v1 = sc * (Zs[(long)i * 256 + dp + 1] - mu) + b[dp + 1];
    v1 = (v1 >= 0.0f) ? v1 : 0.01f * v1;
  }
  Zs[(long)i * 256 + dp]     = v0;
  Zs[(long)i * 256 + dp + 1] = v1;
  if (Outh) {
    int packed = __builtin_amdgcn_cvt_pk_fp8_f32(v0, v1, 0, false);
    Outh[(long)i * 32 + (dp >> 1)] = (unsigned short)packed;
  }
}

// ---- fused fc BN-apply + fc2 dot + sigmoid (reduces SPREAD per block) ----
__global__ __launch_bounds__(256) void fc2bn_kernel(const float* __restrict__ H,
    const float* __restrict__ spread,
    const float* __restrict__ g, const float* __restrict__ b,
    const float* __restrict__ W2, const float* __restrict__ b2,
    float* __restrict__ out) {
  __shared__ float st[128];
  int tid = threadIdx.x;
  if (tid < 128) {
    float a = 0.0f;
    #pragma unroll
    for (int gg = 0; gg < SPREAD; gg++) a += spread[gg * 128 + tid];
    st[tid] = a;
  }
  __syncthreads();
  int k = tid & 63, q = tid >> 6;
  int i = blockIdx.x * 4 + q;
  float invn = 1.0f / (float)NN;
  float mu = st[k] * invn;
  float var = fmaxf(st[64 + k] * invn - mu * mu, 0.0f);
  float sc = g[k] * rsqrtf(var + BN_EPS);
  float v = 0.0f;
  if (i < NN) {
    float hv = sc * (H[(long)i * D + k] - mu) + b[k];
    hv = (hv >= 0.0f) ? hv : 0.01f * hv;
    v = hv * W2[k];
  }
  #pragma unroll
  for (int off = 32; off > 0; off >>= 1)
    v += __shfl_down(v, off);
  if (k == 0 && i < NN) {
    float x = v + b2[0];
    out[i] = 1.0f / (1.0f + __expf(-x));
  }
}

extern "C" void kernel_launch(void* const* d_in, const int* in_sizes, int n_in,
                              void* d_out, int out_size, void* d_ws, size_t ws_size,
                              hipStream_t stream) {
  const int*   node_deg   = (const int*)d_in[0];
  const int*   edge_index = (const int*)d_in[1];
  const float* embedw     = (const float*)d_in[2];
  const float* eps        = (const float*)d_in[3];
  const float* W1         = (const float*)d_in[4];
  const float* b1         = (const float*)d_in[5];
  const float* W2         = (const float*)d_in[6];
  const float* b2         = (const float*)d_in[7];
  const float* bn_g       = (const float*)d_in[8];
  const float* bn_b       = (const float*)d_in[9];
  const float* fc_W1      = (const float*)d_in[10];
  const float* fc_b1      = (const float*)d_in[11];
  const float* fc_bn_g    = (const float*)d_in[12];
  const float* fc_bn_b    = (const float*)d_in[13];
  const float* fc_W2      = (const float*)d_in[14];
  const float* fc_b2      = (const float*)d_in[15];

  float* zcat   = (float*)d_ws;                 // [N,256] (slice 0 unused now)
  float* agg    = zcat + (long)NN * 256;        // [N,64]
  float* statsS = agg + (long)NN * D;           // 4 * SPREAD*128
  float* statsF = statsS + 4 * SPREAD * 128;    // layout keep
  int*   csroff = (int*)(statsF + 512);         // [NN+1]
  int*   bsum   = csroff + NN + 1;              // [512]
  int*   csrsrc = bsum + 512;                   // [NE]
  int*   rec    = csrsrc + NE;                  // [NE]
  int*   S      = rec + NE;                     // [NP*392]
  unsigned* cnt8 = (unsigned*)(S + NP * 392);   // [N,16] u32
  float* E1     = (float*)(cnt8 + (long)NN * 16);  // [64,64]
  float* Tt     = E1 + 64 * 64;                    // [64,64]
  unsigned short* xh = (unsigned short*)rec;    // fp8 mirror [N][64] overlays rec

  const int rowBlocks   = NN / 4;                 // 25000
  const int layerBlocks = (NN + 63) / 64;         // 1563
  const int aggBlocks   = NN / 16;                // 6250
  const int bnBlocks    = (NN * 32 + 255) / 256;  // 12500

  precompute_kernel<<<2, 256, 0, stream>>>(embedw, W1, fc_W1, E1, Tt);
  bucket_kernel<<<NP, 256, 0, stream>>>(edge_index, node_deg, rec, S);
  bucketsum_kernel<<<NB, 256, 0, stream>>>(S, bsum);
  scan2_kernel<<<1, 512, 0, stream>>>(bsum);
  sort_kernel<<<NB, 512, 0, stream>>>(rec, S, bsum, csroff, csrsrc, cnt8);

  hipMemsetAsync(statsS, 0, (size_t)(4 * SPREAD * 128) * sizeof(float), stream);

  for (int l = 0; l < 3; ++l) {
    if (l > 0)
      agg_kernel<<<aggBlocks, 256, 0, stream>>>(csroff, csrsrc,
          (const unsigned*)xh, agg);
    layer_kernel<<<layerBlocks, 256, 0, stream>>>(zcat + l * D,
        (l == 0) ? nullptr : agg,
        (l == 0) ? cnt8 : nullptr, E1, node_deg,
        eps, l,
        W1 + (long)l * D * D, b1 + (long)l * D,
        W2 + (long)l * D * D, b2 + (long)l * D,
        zcat + (l + 1) * D, statsS + (long)l * SPREAD * 128);
    bn_apply_kernel<<<bnBlocks, 256, 0, stream>>>(zcat + (l + 1) * D,
        statsS + (long)l * SPREAD * 128,
        bn_g + (long)l * D, bn_b + (long)l * D,
        (l < 2) ? xh : nullptr);
  }

  fc1_kernel<<<layerBlocks, 256, 0, stream>>>(zcat, node_deg, Tt,
      fc_W1, fc_b1, agg, statsS + 3L * SPREAD * 128);
  fc2bn_kernel<<<rowBlocks, 256, 0, stream>>>(agg, statsS + 3L * SPREAD * 128,
      fc_bn_g, fc_bn_b, fc_W2, fc_b2, (float*)d_out);
}